// Round 17
// baseline (373.279 us; speedup 1.0000x reference)
//
#include <hip/hip_runtime.h>
#include <hip/hip_bf16.h>
#include <stdint.h>

// B=2048, D=1024, H=8, DH=64, INNER=512; attention over flattened (B*H)=16384 axis.
// fp32 in/out. Pipeline:
//   prep_all: x->xb bf16; weights -> transposed bf16
//   GEMM-1 (depth-1 reg pipeline, r15-proven): xb @ WtQKV^T -> QK (pre-scaled) + Vt
//   flash attention r17: S^T formulation with REGISTER-PEAK-REDUCED inner loop
//     (per-jb processing: s live 32 not 64, pf live 16 not 32) + launch_bounds(256,3)
//     -> 3 waves/SIMD (was reg-capped at 2); nsplit=16 feeds 3 blocks/CU.
//   merge -> GEMM-2: Ob @ WtOut^T + bias -> fp32 out.
// ws: QK 4M | Vt 2M | Ob 2M | WtOut 1M | {xb 4M, WtQKV 3M ==overlaid==> accP+lP}.

typedef __bf16 bf16_t;
typedef __bf16 bf16x4 __attribute__((ext_vector_type(4)));
typedef __bf16 bf16x8 __attribute__((ext_vector_type(8)));
typedef float floatx4 __attribute__((ext_vector_type(4)));

__device__ __forceinline__ floatx4 mfma16(bf16x8 a, bf16x8 b, floatx4 c) {
    return __builtin_amdgcn_mfma_f32_16x16x32_bf16(a, b, c, 0, 0, 0);
}

__device__ __forceinline__ bf16x8 cvt8(float4 a, float4 b) {
    bf16x8 o;
    o[0] = (bf16_t)a.x; o[1] = (bf16_t)a.y; o[2] = (bf16_t)a.z; o[3] = (bf16_t)a.w;
    o[4] = (bf16_t)b.x; o[5] = (bf16_t)b.y; o[6] = (bf16_t)b.z; o[7] = (bf16_t)b.w;
    return o;
}

// ---------------- fused prep (r14, unchanged) ----------------
__device__ __forceinline__ void transpose_body(const float* __restrict__ in, int N,
                                               bf16_t* __restrict__ out, int ldo,
                                               int bx, int by, int tid, float (*tile)[33]) {
    int n0 = bx * 32, k0 = by * 32;
    int tx = tid & 31, ty = tid >> 5;
#pragma unroll
    for (int i = 0; i < 32; i += 8)
        tile[ty + i][tx] = in[(size_t)(k0 + ty + i) * N + (n0 + tx)];
    __syncthreads();
#pragma unroll
    for (int i = 0; i < 32; i += 8)
        out[(size_t)(n0 + ty + i) * ldo + (k0 + tx)] = (bf16_t)tile[tx][ty + i];
}

__global__ __launch_bounds__(256) void prep_all(const float* __restrict__ x,
                                                bf16_t* __restrict__ xb,
                                                const float* __restrict__ Wq,
                                                const float* __restrict__ Wkv,
                                                const float* __restrict__ Wout,
                                                bf16_t* __restrict__ WtQKV,
                                                bf16_t* __restrict__ WtOut) {
    __shared__ float tile[32][33];
    int b = blockIdx.x, tid = threadIdx.x;
    if (b < 1024) {
        int i = (b * 256 + tid) * 8;
        *(bf16x8*)(xb + i) = cvt8(*(const float4*)(x + i), *(const float4*)(x + i + 4));
    } else if (b < 1536) {
        b -= 1024;
        transpose_body(Wq, 512, WtQKV, 1024, b & 15, b >> 4, tid, tile);
    } else if (b < 2560) {
        b -= 1536;
        transpose_body(Wkv, 1024, WtQKV + 512 * 1024, 1024, b & 31, b >> 5, tid, tile);
    } else {
        b -= 2560;
        transpose_body(Wout, 1024, WtOut, 512, b & 31, b >> 5, tid, tile);
    }
}

// ---------------- GEMM: C = A @ Bt^T, BK=64, depth-1 reg pipeline (r15-proven) --------
template <int OF32, int MI>
__global__ __launch_bounds__(256) void gemm_bt(const bf16_t* __restrict__ A,
                                               const bf16_t* __restrict__ Bt,
                                               const float* __restrict__ bias,
                                               void* __restrict__ Cout,
                                               bf16_t* __restrict__ VtOut, int vt_col0,
                                               int K, int lda, int ldb, int ldc,
                                               float qscale, int qcols) {
    constexpr int MT = MI * 32;
    constexpr int PA = MT / 64;
    __shared__ bf16_t sA[MT * 64];
    __shared__ bf16_t sB[64 * 64];
    int tid = threadIdx.x;
    int wave = tid >> 6, lane = tid & 63;
    int lm = lane & 15, q = lane >> 4;
    int bm = blockIdx.x * MT, bn = blockIdx.y * 64;
    int wm = (wave >> 1) * (MT / 2), wn = (wave & 1) * 32;

    int c0 = (tid & 3) * 2, c1 = c0 + 1;
    int rA[PA], swA[PA];
    size_t srcA0[PA], srcA1[PA];
#pragma unroll
    for (int p = 0; p < PA; ++p) {
        rA[p] = p * 64 + (tid >> 2);
        swA[p] = rA[p] & 7;
        srcA0[p] = (size_t)(bm + rA[p]) * lda + ((c0 ^ swA[p]) << 3);
        srcA1[p] = (size_t)(bm + rA[p]) * lda + ((c1 ^ swA[p]) << 3);
    }
    int rB = tid >> 2, swB = rB & 7;
    size_t srcB0 = (size_t)(bn + rB) * ldb + ((c0 ^ swB) << 3);
    size_t srcB1 = (size_t)(bn + rB) * ldb + ((c1 ^ swB) << 3);

    floatx4 acc[MI][2];
#pragma unroll
    for (int i = 0; i < MI; ++i)
#pragma unroll
        for (int j = 0; j < 2; ++j) acc[i][j] = (floatx4){0.f, 0.f, 0.f, 0.f};

    bf16x8 pa0[PA], pa1[PA], pb0, pb1;
#pragma unroll
    for (int p = 0; p < PA; ++p) {
        pa0[p] = *(const bf16x8*)(A + srcA0[p]);
        pa1[p] = *(const bf16x8*)(A + srcA1[p]);
    }
    pb0 = *(const bf16x8*)(Bt + srcB0);
    pb1 = *(const bf16x8*)(Bt + srcB1);
#pragma unroll
    for (int p = 0; p < PA; ++p) {
        *(bf16x8*)&sA[p * 4096 + tid * 16] = pa0[p];
        *(bf16x8*)&sA[p * 4096 + tid * 16 + 8] = pa1[p];
    }
    *(bf16x8*)&sB[tid * 16] = pb0;
    *(bf16x8*)&sB[tid * 16 + 8] = pb1;
    __syncthreads();

    for (int k0 = 0; k0 < K; k0 += 64) {
        int kn = (k0 + 64 < K) ? k0 + 64 : 0;
#pragma unroll
        for (int p = 0; p < PA; ++p) {
            pa0[p] = *(const bf16x8*)(A + srcA0[p] + kn);
            pa1[p] = *(const bf16x8*)(A + srcA1[p] + kn);
        }
        pb0 = *(const bf16x8*)(Bt + srcB0 + kn);
        pb1 = *(const bf16x8*)(Bt + srcB1 + kn);

#pragma unroll
        for (int s = 0; s < 2; ++s) {
            int cs = s * 4 + q;
            bf16x8 af[MI], bfr[2];
#pragma unroll
            for (int i = 0; i < MI; ++i) {
                int row = wm + i * 16 + lm;
                af[i] = *(bf16x8*)&sA[row * 64 + ((cs ^ (lm & 7)) << 3)];
            }
#pragma unroll
            for (int j = 0; j < 2; ++j) {
                int row = wn + j * 16 + lm;
                bfr[j] = *(bf16x8*)&sB[row * 64 + ((cs ^ (lm & 7)) << 3)];
            }
#pragma unroll
            for (int i = 0; i < MI; ++i)
#pragma unroll
                for (int j = 0; j < 2; ++j)
                    acc[i][j] = mfma16(af[i], bfr[j], acc[i][j]);
        }

        __syncthreads();
#pragma unroll
        for (int p = 0; p < PA; ++p) {
            *(bf16x8*)&sA[p * 4096 + tid * 16] = pa0[p];
            *(bf16x8*)&sA[p * 4096 + tid * 16 + 8] = pa1[p];
        }
        *(bf16x8*)&sB[tid * 16] = pb0;
        *(bf16x8*)&sB[tid * 16 + 8] = pb1;
        __syncthreads();
    }

    // C/D layout: col = lane&15, row = (lane>>4)*4 + reg  [m89/m91 verified]
#pragma unroll
    for (int i = 0; i < MI; ++i)
#pragma unroll
        for (int j = 0; j < 2; ++j)
#pragma unroll
            for (int r = 0; r < 4; ++r) {
                int row = bm + wm + i * 16 + q * 4 + r;
                int col = bn + wn + j * 16 + lm;
                float v = acc[i][j][r];
                if (col < qcols) v *= qscale;
                if (bias) v += bias[col];
                if (col >= vt_col0) {
                    int cc = col - vt_col0;
                    VtOut[(size_t)(cc & 63) * 16384 + row * 8 + (cc >> 6)] = (bf16_t)v;
                } else {
                    size_t off = (size_t)row * ldc + col;
                    if (OF32) ((float*)Cout)[off] = v;
                    else      ((bf16_t*)Cout)[off] = (bf16_t)v;
                }
            }
}

// ---------------- flash attention r17: S^T, register-peak-reduced inner loop ----------
// Per-jb processing: S for 2 nb-tiles (32 regs) -> exp2+pack (pf 16 regs) -> PV
// immediately. Peak regs ~160 -> 3 waves/SIMD (launch_bounds-enforced).
__global__ __launch_bounds__(256, 3) void flash_attn(const bf16_t* __restrict__ QK,
                                                     const bf16_t* __restrict__ Vt,
                                                     bf16_t* __restrict__ O,
                                                     float* __restrict__ accP,
                                                     float* __restrict__ lP,
                                                     int kps, int nsplit) {
    __shared__ bf16_t sK[64 * 64];   // (sigma-permuted key, dh-chunk')
    __shared__ bf16_t sVt[64 * 64];  // (dh, natural key-chunk')
    int tid = threadIdx.x;
    int wave = tid >> 6, lane = tid & 63;
    int lm = lane & 15, q = lane >> 4;
    int sp = blockIdx.y;
    int qrow0 = blockIdx.x * 256 + wave * 64;

    bf16x8 qf[4][2];
#pragma unroll
    for (int sub = 0; sub < 4; ++sub) {
        int qr = qrow0 + sub * 16 + lm;
        const bf16_t* qp = QK + (size_t)(qr >> 3) * 1024 + (qr & 7) * 64;
        qf[sub][0] = *(const bf16x8*)(qp + q * 8);
        qf[sub][1] = *(const bf16x8*)(qp + 32 + q * 8);
    }

    int sr = tid >> 2;
    int ch0 = (tid & 3) * 2, ch1 = ch0 + 1;
    int swz = sr & 7;
    int lsr = 32 * (sr >> 5) + 8 * ((sr >> 2) & 3) + 4 * ((sr >> 4) & 1) + (sr & 3);
    int ksrcA = (lsr >> 3) * 1024 + (lsr & 7) * 64 + 512 + ((ch0 ^ swz) << 3);
    int ksrcB = (lsr >> 3) * 1024 + (lsr & 7) * 64 + 512 + ((ch1 ^ swz) << 3);
    size_t vsrcA = (size_t)sr * 16384 + ((ch0 ^ swz) << 3);
    size_t vsrcB = (size_t)sr * 16384 + ((ch1 ^ swz) << 3);
    bf16_t* dK = &sK[tid * 16];
    bf16_t* dV = &sVt[tid * 16];

    int c0 = q ^ (lm & 7);

    floatx4 acc[4][4];
#pragma unroll
    for (int sub = 0; sub < 4; ++sub)
#pragma unroll
        for (int i = 0; i < 4; ++i) acc[sub][i] = (floatx4){0.f, 0.f, 0.f, 0.f};
    float lacc[4] = {0.f, 0.f, 0.f, 0.f};

    int kt0 = sp * kps, kend = kt0 + kps;

    bf16x8 krA, krB, vrA, vrB;
    {
        const bf16_t* kb = QK + (size_t)kt0 * 128;
        krA = *(const bf16x8*)(kb + ksrcA);
        krB = *(const bf16x8*)(kb + ksrcB);
        vrA = *(const bf16x8*)(Vt + vsrcA + kt0);
        vrB = *(const bf16x8*)(Vt + vsrcB + kt0);
    }
    *(bf16x8*)dK = krA; *(bf16x8*)(dK + 8) = krB;
    *(bf16x8*)dV = vrA; *(bf16x8*)(dV + 8) = vrB;
    __syncthreads();

    for (int kt = kt0; kt < kend; kt += 64) {
        int ktn = (kt + 64 < kend) ? kt + 64 : kt0;
        const bf16_t* kbn = QK + (size_t)ktn * 128;
        krA = *(const bf16x8*)(kbn + ksrcA);
        krB = *(const bf16x8*)(kbn + ksrcB);
        vrA = *(const bf16x8*)(Vt + vsrcA + ktn);
        vrB = *(const bf16x8*)(Vt + vsrcB + ktn);

        // per-jb: S^T for tiles {2jb, 2jb+1} -> exp2+pack -> PV, minimizing live regs
#pragma unroll
        for (int jb = 0; jb < 2; ++jb) {
            floatx4 s[4][2];
#pragma unroll
            for (int p2 = 0; p2 < 2; ++p2) {
                int nb = jb * 2 + p2;
                int row = (nb * 16 + lm) * 64;
                bf16x8 k0 = *(bf16x8*)&sK[row + (c0 << 3)];
                bf16x8 k1 = *(bf16x8*)&sK[row + ((c0 ^ 4) << 3)];
#pragma unroll
                for (int sub = 0; sub < 4; ++sub) {
                    floatx4 a = (floatx4){0.f, 0.f, 0.f, 0.f};
                    a = mfma16(k0, qf[sub][0], a);
                    a = mfma16(k1, qf[sub][1], a);
                    s[sub][p2] = a;
                }
            }
            bf16x8 av[4];
#pragma unroll
            for (int nd = 0; nd < 4; ++nd)
                av[nd] = *(bf16x8*)&sVt[(nd * 16 + lm) * 64 + ((c0 ^ (jb << 2)) << 3)];
#pragma unroll
            for (int sub = 0; sub < 4; ++sub) {
                bf16x8 p;
#pragma unroll
                for (int r = 0; r < 4; ++r) {
                    float p0 = __builtin_amdgcn_exp2f(s[sub][0][r]);
                    float p1 = __builtin_amdgcn_exp2f(s[sub][1][r]);
                    lacc[sub] += p0 + p1;
                    p[r] = (bf16_t)p0;
                    p[r + 4] = (bf16_t)p1;
                }
#pragma unroll
                for (int nd = 0; nd < 4; ++nd)
                    acc[sub][nd] = mfma16(av[nd], p, acc[sub][nd]);
            }
        }

        __syncthreads();
        *(bf16x8*)dK = krA; *(bf16x8*)(dK + 8) = krB;
        *(bf16x8*)dV = vrA; *(bf16x8*)(dV + 8) = vrB;
        __syncthreads();
    }

    // l reduction across quads (each quad holds a disjoint key subset)
#pragma unroll
    for (int sub = 0; sub < 4; ++sub) {
        lacc[sub] += __shfl_xor(lacc[sub], 16);
        lacc[sub] += __shfl_xor(lacc[sub], 32);
    }

    if (nsplit == 1) {
#pragma unroll
        for (int sub = 0; sub < 4; ++sub) {
            float inv = 1.f / lacc[sub];
            int row = qrow0 + sub * 16 + lm;
#pragma unroll
            for (int nd = 0; nd < 4; ++nd) {
                bf16x4 o;
#pragma unroll
                for (int r = 0; r < 4; ++r) o[r] = (bf16_t)(acc[sub][nd][r] * inv);
                *(bf16x4*)&O[(size_t)row * 64 + nd * 16 + q * 4] = o;
            }
        }
    } else {
#pragma unroll
        for (int sub = 0; sub < 4; ++sub) {
            int row = qrow0 + sub * 16 + lm;
            size_t base = ((size_t)sp * 16384 + row) * 64;
#pragma unroll
            for (int nd = 0; nd < 4; ++nd) {
                float4 v = {acc[sub][nd][0], acc[sub][nd][1],
                            acc[sub][nd][2], acc[sub][nd][3]};
                *(float4*)&accP[base + nd * 16 + q * 4] = v;
            }
            if (lane < 16) lP[sp * 16384 + row] = lacc[sub];
        }
    }
}

// ---------------- merge key-split partials (plain sums) ----------------
__global__ __launch_bounds__(256) void merge_attn(const float* __restrict__ accP,
                                                  const float* __restrict__ lP,
                                                  bf16_t* __restrict__ O, int nsplit) {
    int idx = blockIdx.x * 256 + threadIdx.x;
    int row = idx >> 4, dh4 = (idx & 15) * 4;
    float4 num = {0.f, 0.f, 0.f, 0.f};
    float den = 0.f;
    for (int s = 0; s < nsplit; ++s) {
        float4 a = *(const float4*)&accP[((size_t)s * 16384 + row) * 64 + dh4];
        num.x += a.x; num.y += a.y; num.z += a.z; num.w += a.w;
        den += lP[s * 16384 + row];
    }
    float inv = 1.f / den;
    bf16x4 o;
    o[0] = (bf16_t)(num.x * inv); o[1] = (bf16_t)(num.y * inv);
    o[2] = (bf16_t)(num.z * inv); o[3] = (bf16_t)(num.w * inv);
    *(bf16x4*)&O[(size_t)row * 64 + dh4] = o;
}

// ---------------- launch ----------------
extern "C" void kernel_launch(void* const* d_in, const int* in_sizes, int n_in,
                              void* d_out, int out_size, void* d_ws, size_t ws_size,
                              hipStream_t stream) {
    const float* x    = (const float*)d_in[0];  // 2048 x 1024
    const float* Wq   = (const float*)d_in[1];  // 1024 x 512
    const float* Wkv  = (const float*)d_in[2];  // 1024 x 1024
    const float* Wout = (const float*)d_in[3];  // 512 x 1024
    const float* bout = (const float*)d_in[4];  // 1024

    char* ws = (char*)d_ws;
    bf16_t* QK    = (bf16_t*)ws;                // 4M
    bf16_t* Vt    = (bf16_t*)(ws + 4194304);    // 2M
    bf16_t* Ob    = (bf16_t*)(ws + 6291456);    // 2M
    bf16_t* WtOut = (bf16_t*)(ws + 8388608);    // 1M (lives until GEMM-2)
    bf16_t* xb    = (bf16_t*)(ws + 9437184);    // 4M (dead after GEMM-1)
    bf16_t* WtQKV = (bf16_t*)(ws + 13631488);   // 3M (dead after GEMM-1)
    float*  accP  = (float*)(ws + 9437184);     // OVERLAYS xb/WtQKV (flash writes
                                                // strictly after GEMM-1 reads)

    int nsplit = (ws_size >= (size_t)9437184 + 16 * 4259840) ? 16
               : (ws_size >= (size_t)9437184 + 8 * 4259840)  ? 8
               : (ws_size >= (size_t)9437184 + 4 * 4259840)  ? 4
               : (ws_size >= (size_t)9437184 + 2 * 4259840)  ? 2 : 1;
    float* lP = (float*)(ws + 9437184 + (size_t)nsplit * 4194304);

    prep_all<<<3072, 256, 0, stream>>>(x, xb, Wq, Wkv, Wout, WtQKV, WtOut);

    // [QK | Vt] = xb @ WtQKV^T; Q cols scaled by DH^-0.5*log2(e); V cols transposed
    gemm_bt<0, 2><<<dim3(32, 24), 256, 0, stream>>>(
        xb, WtQKV, nullptr, QK, Vt, 1024, 1024, 1024, 1024, 1024,
        0.18033688011112042f, 512);

    flash_attn<<<dim3(64, nsplit), 256, 0, stream>>>(QK, Vt, Ob, accP, lP,
                                                     16384 / nsplit, nsplit);
    if (nsplit > 1)
        merge_attn<<<1024, 256, 0, stream>>>(accP, lP, Ob, nsplit);

    // out = Ob @ WtOut^T + bout (fp32 out)
    gemm_bt<1, 2><<<dim3(32, 16), 256, 0, stream>>>(
        Ob, WtOut, bout, d_out, nullptr, 1 << 30, 512, 512, 512, 1024,
        1.0f, 0);
}

// Round 18
// 173.444 us; speedup vs baseline: 2.1522x; 2.1522x over previous
//
#include <hip/hip_runtime.h>
#include <hip/hip_bf16.h>
#include <stdint.h>

// B=2048, D=1024, H=8, DH=64, INNER=512; attention over flattened (B*H)=16384 axis.
// fp32 in/out. r18 = r15 champion + SINGLE-BARRIER K-loops (double-buffered LDS in
// flash and both GEMMs: compute from buf p, deposit prefetch into buf 1-p, one
// __syncthreads per tile — halves the full-drain barrier stalls).
//   prep_all: x->xb bf16; weights -> transposed bf16
//   GEMM-1: xb @ WtQKV^T -> QK (Q pre-scaled) + Vt  (reg prefetch + LDS dbuf)
//   flash r15 S^T formulation (exp2 regs ARE the PV B-operand; no sP) + LDS dbuf
//   merge -> GEMM-2: Ob @ WtOut^T + bias -> fp32 out.
// ws: QK 4M | Vt 2M | Ob 2M | xb 4M | WtQKV 3M | WtOut 1M | accP ns*4M | lP ns*64K.

typedef __bf16 bf16_t;
typedef __bf16 bf16x4 __attribute__((ext_vector_type(4)));
typedef __bf16 bf16x8 __attribute__((ext_vector_type(8)));
typedef float floatx4 __attribute__((ext_vector_type(4)));

__device__ __forceinline__ floatx4 mfma16(bf16x8 a, bf16x8 b, floatx4 c) {
    return __builtin_amdgcn_mfma_f32_16x16x32_bf16(a, b, c, 0, 0, 0);
}

__device__ __forceinline__ bf16x8 cvt8(float4 a, float4 b) {
    bf16x8 o;
    o[0] = (bf16_t)a.x; o[1] = (bf16_t)a.y; o[2] = (bf16_t)a.z; o[3] = (bf16_t)a.w;
    o[4] = (bf16_t)b.x; o[5] = (bf16_t)b.y; o[6] = (bf16_t)b.z; o[7] = (bf16_t)b.w;
    return o;
}

// ---------------- fused prep (r14, unchanged) ----------------
__device__ __forceinline__ void transpose_body(const float* __restrict__ in, int N,
                                               bf16_t* __restrict__ out, int ldo,
                                               int bx, int by, int tid, float (*tile)[33]) {
    int n0 = bx * 32, k0 = by * 32;
    int tx = tid & 31, ty = tid >> 5;
#pragma unroll
    for (int i = 0; i < 32; i += 8)
        tile[ty + i][tx] = in[(size_t)(k0 + ty + i) * N + (n0 + tx)];
    __syncthreads();
#pragma unroll
    for (int i = 0; i < 32; i += 8)
        out[(size_t)(n0 + ty + i) * ldo + (k0 + tx)] = (bf16_t)tile[tx][ty + i];
}

__global__ __launch_bounds__(256) void prep_all(const float* __restrict__ x,
                                                bf16_t* __restrict__ xb,
                                                const float* __restrict__ Wq,
                                                const float* __restrict__ Wkv,
                                                const float* __restrict__ Wout,
                                                bf16_t* __restrict__ WtQKV,
                                                bf16_t* __restrict__ WtOut) {
    __shared__ float tile[32][33];
    int b = blockIdx.x, tid = threadIdx.x;
    if (b < 1024) {
        int i = (b * 256 + tid) * 8;
        *(bf16x8*)(xb + i) = cvt8(*(const float4*)(x + i), *(const float4*)(x + i + 4));
    } else if (b < 1536) {
        b -= 1024;
        transpose_body(Wq, 512, WtQKV, 1024, b & 15, b >> 4, tid, tile);
    } else if (b < 2560) {
        b -= 1536;
        transpose_body(Wkv, 1024, WtQKV + 512 * 1024, 1024, b & 31, b >> 5, tid, tile);
    } else {
        b -= 2560;
        transpose_body(Wout, 1024, WtOut, 512, b & 31, b >> 5, tid, tile);
    }
}

// ------- GEMM: C = A @ Bt^T, BK=64, reg prefetch + LDS double-buffer (1 barrier) ------
template <int OF32, int MI>
__global__ __launch_bounds__(256) void gemm_bt(const bf16_t* __restrict__ A,
                                               const bf16_t* __restrict__ Bt,
                                               const float* __restrict__ bias,
                                               void* __restrict__ Cout,
                                               bf16_t* __restrict__ VtOut, int vt_col0,
                                               int K, int lda, int ldb, int ldc,
                                               float qscale, int qcols) {
    constexpr int MT = MI * 32;
    constexpr int PA = MT / 64;
    constexpr int ABUF = MT * 64;
    __shared__ bf16_t sA[2 * ABUF];
    __shared__ bf16_t sB[2 * 4096];
    int tid = threadIdx.x;
    int wave = tid >> 6, lane = tid & 63;
    int lm = lane & 15, q = lane >> 4;
    int bm = blockIdx.x * MT, bn = blockIdx.y * 64;
    int wm = (wave >> 1) * (MT / 2), wn = (wave & 1) * 32;

    int c0 = (tid & 3) * 2, c1 = c0 + 1;
    int rA[PA], swA[PA];
    size_t srcA0[PA], srcA1[PA];
#pragma unroll
    for (int p = 0; p < PA; ++p) {
        rA[p] = p * 64 + (tid >> 2);
        swA[p] = rA[p] & 7;
        srcA0[p] = (size_t)(bm + rA[p]) * lda + ((c0 ^ swA[p]) << 3);
        srcA1[p] = (size_t)(bm + rA[p]) * lda + ((c1 ^ swA[p]) << 3);
    }
    int rB = tid >> 2, swB = rB & 7;
    size_t srcB0 = (size_t)(bn + rB) * ldb + ((c0 ^ swB) << 3);
    size_t srcB1 = (size_t)(bn + rB) * ldb + ((c1 ^ swB) << 3);

    floatx4 acc[MI][2];
#pragma unroll
    for (int i = 0; i < MI; ++i)
#pragma unroll
        for (int j = 0; j < 2; ++j) acc[i][j] = (floatx4){0.f, 0.f, 0.f, 0.f};

    bf16x8 pa0[PA], pa1[PA], pb0, pb1;
#pragma unroll
    for (int p = 0; p < PA; ++p) {
        pa0[p] = *(const bf16x8*)(A + srcA0[p]);
        pa1[p] = *(const bf16x8*)(A + srcA1[p]);
    }
    pb0 = *(const bf16x8*)(Bt + srcB0);
    pb1 = *(const bf16x8*)(Bt + srcB1);
#pragma unroll
    for (int p = 0; p < PA; ++p) {
        *(bf16x8*)&sA[p * 4096 + tid * 16] = pa0[p];
        *(bf16x8*)&sA[p * 4096 + tid * 16 + 8] = pa1[p];
    }
    *(bf16x8*)&sB[tid * 16] = pb0;
    *(bf16x8*)&sB[tid * 16 + 8] = pb1;
    __syncthreads();

    int po = 0;  // parity offset into the double buffers
    for (int k0 = 0; k0 < K; k0 += 64) {
        int kn = (k0 + 64 < K) ? k0 + 64 : 0;
#pragma unroll
        for (int p = 0; p < PA; ++p) {
            pa0[p] = *(const bf16x8*)(A + srcA0[p] + kn);
            pa1[p] = *(const bf16x8*)(A + srcA1[p] + kn);
        }
        pb0 = *(const bf16x8*)(Bt + srcB0 + kn);
        pb1 = *(const bf16x8*)(Bt + srcB1 + kn);

        // compute current tile from buffer po
#pragma unroll
        for (int s = 0; s < 2; ++s) {
            int cs = s * 4 + q;
            bf16x8 af[MI], bfr[2];
#pragma unroll
            for (int i = 0; i < MI; ++i) {
                int row = wm + i * 16 + lm;
                af[i] = *(bf16x8*)&sA[po * ABUF + row * 64 + ((cs ^ (lm & 7)) << 3)];
            }
#pragma unroll
            for (int j = 0; j < 2; ++j) {
                int row = wn + j * 16 + lm;
                bfr[j] = *(bf16x8*)&sB[po * 4096 + row * 64 + ((cs ^ (lm & 7)) << 3)];
            }
#pragma unroll
            for (int i = 0; i < MI; ++i)
#pragma unroll
                for (int j = 0; j < 2; ++j)
                    acc[i][j] = mfma16(af[i], bfr[j], acc[i][j]);
        }

        // deposit prefetched tile into the OTHER buffer; single barrier publishes it
        int qo = po ^ 1;
#pragma unroll
        for (int p = 0; p < PA; ++p) {
            *(bf16x8*)&sA[qo * ABUF + p * 4096 + tid * 16] = pa0[p];
            *(bf16x8*)&sA[qo * ABUF + p * 4096 + tid * 16 + 8] = pa1[p];
        }
        *(bf16x8*)&sB[qo * 4096 + tid * 16] = pb0;
        *(bf16x8*)&sB[qo * 4096 + tid * 16 + 8] = pb1;
        __syncthreads();
        po = qo;
    }

    // C/D layout: col = lane&15, row = (lane>>4)*4 + reg  [m89/m91 verified]
#pragma unroll
    for (int i = 0; i < MI; ++i)
#pragma unroll
        for (int j = 0; j < 2; ++j)
#pragma unroll
            for (int r = 0; r < 4; ++r) {
                int row = bm + wm + i * 16 + q * 4 + r;
                int col = bn + wn + j * 16 + lm;
                float v = acc[i][j][r];
                if (col < qcols) v *= qscale;
                if (bias) v += bias[col];
                if (col >= vt_col0) {
                    int cc = col - vt_col0;
                    VtOut[(size_t)(cc & 63) * 16384 + row * 8 + (cc >> 6)] = (bf16_t)v;
                } else {
                    size_t off = (size_t)row * ldc + col;
                    if (OF32) ((float*)Cout)[off] = v;
                    else      ((bf16_t*)Cout)[off] = (bf16_t)v;
                }
            }
}

// ------- flash attention r15 (S^T formulation) + LDS double-buffer (1 barrier) --------
__global__ __launch_bounds__(256, 2) void flash_attn(const bf16_t* __restrict__ QK,
                                                     const bf16_t* __restrict__ Vt,
                                                     bf16_t* __restrict__ O,
                                                     float* __restrict__ accP,
                                                     float* __restrict__ lP,
                                                     int kps, int nsplit) {
    __shared__ bf16_t sK[2 * 4096];   // (sigma-permuted key, dh-chunk') x2 buffers
    __shared__ bf16_t sVt[2 * 4096];  // (dh, natural key-chunk') x2 buffers
    int tid = threadIdx.x;
    int wave = tid >> 6, lane = tid & 63;
    int lm = lane & 15, q = lane >> 4;
    int sp = blockIdx.y;
    int qrow0 = blockIdx.x * 256 + wave * 64;

    bf16x8 qf[4][2];
#pragma unroll
    for (int sub = 0; sub < 4; ++sub) {
        int qr = qrow0 + sub * 16 + lm;
        const bf16_t* qp = QK + (size_t)(qr >> 3) * 1024 + (qr & 7) * 64;
        qf[sub][0] = *(const bf16x8*)(qp + q * 8);
        qf[sub][1] = *(const bf16x8*)(qp + 32 + q * 8);
    }

    int sr = tid >> 2;
    int ch0 = (tid & 3) * 2, ch1 = ch0 + 1;
    int swz = sr & 7;
    int lsr = 32 * (sr >> 5) + 8 * ((sr >> 2) & 3) + 4 * ((sr >> 4) & 1) + (sr & 3);
    int ksrcA = (lsr >> 3) * 1024 + (lsr & 7) * 64 + 512 + ((ch0 ^ swz) << 3);
    int ksrcB = (lsr >> 3) * 1024 + (lsr & 7) * 64 + 512 + ((ch1 ^ swz) << 3);
    size_t vsrcA = (size_t)sr * 16384 + ((ch0 ^ swz) << 3);
    size_t vsrcB = (size_t)sr * 16384 + ((ch1 ^ swz) << 3);

    int c0 = q ^ (lm & 7);

    floatx4 acc[4][4];
#pragma unroll
    for (int sub = 0; sub < 4; ++sub)
#pragma unroll
        for (int i = 0; i < 4; ++i) acc[sub][i] = (floatx4){0.f, 0.f, 0.f, 0.f};
    float lacc[4] = {0.f, 0.f, 0.f, 0.f};

    int kt0 = sp * kps, kend = kt0 + kps;

    bf16x8 krA, krB, vrA, vrB;
    {
        const bf16_t* kb = QK + (size_t)kt0 * 128;
        krA = *(const bf16x8*)(kb + ksrcA);
        krB = *(const bf16x8*)(kb + ksrcB);
        vrA = *(const bf16x8*)(Vt + vsrcA + kt0);
        vrB = *(const bf16x8*)(Vt + vsrcB + kt0);
    }
    *(bf16x8*)&sK[tid * 16] = krA; *(bf16x8*)&sK[tid * 16 + 8] = krB;
    *(bf16x8*)&sVt[tid * 16] = vrA; *(bf16x8*)&sVt[tid * 16 + 8] = vrB;
    __syncthreads();

    int po = 0;
    for (int kt = kt0; kt < kend; kt += 64) {
        int ktn = (kt + 64 < kend) ? kt + 64 : kt0;
        const bf16_t* kbn = QK + (size_t)ktn * 128;
        krA = *(const bf16x8*)(kbn + ksrcA);
        krB = *(const bf16x8*)(kbn + ksrcB);
        vrA = *(const bf16x8*)(Vt + vsrcA + ktn);
        vrB = *(const bf16x8*)(Vt + vsrcB + ktn);

        // S^T = K Q^T from buffer po
        floatx4 s[4][4];
#pragma unroll
        for (int nb = 0; nb < 4; ++nb) {
            int row = po * 4096 + (nb * 16 + lm) * 64;
            bf16x8 k0 = *(bf16x8*)&sK[row + (c0 << 3)];
            bf16x8 k1 = *(bf16x8*)&sK[row + ((c0 ^ 4) << 3)];
#pragma unroll
            for (int sub = 0; sub < 4; ++sub) {
                floatx4 a = (floatx4){0.f, 0.f, 0.f, 0.f};
                a = mfma16(k0, qf[sub][0], a);
                a = mfma16(k1, qf[sub][1], a);
                s[sub][nb] = a;
            }
        }

        // P^T = exp2(S^T); pack into PV B-operands (keys 32jb+8q+j by sigma)
        bf16x8 pf[4][2];
#pragma unroll
        for (int sub = 0; sub < 4; ++sub) {
#pragma unroll
            for (int nb = 0; nb < 4; ++nb)
#pragma unroll
                for (int r = 0; r < 4; ++r) {
                    float pv = __builtin_amdgcn_exp2f(s[sub][nb][r]);
                    s[sub][nb][r] = pv;
                    lacc[sub] += pv;
                }
#pragma unroll
            for (int jb = 0; jb < 2; ++jb) {
                bf16x8 p;
#pragma unroll
                for (int r = 0; r < 4; ++r) {
                    p[r] = (bf16_t)s[sub][2 * jb][r];
                    p[r + 4] = (bf16_t)s[sub][2 * jb + 1][r];
                }
                pf[sub][jb] = p;
            }
        }

        // O^T += V^T P^T from buffer po
#pragma unroll
        for (int jb = 0; jb < 2; ++jb) {
            bf16x8 av[4];
#pragma unroll
            for (int nd = 0; nd < 4; ++nd)
                av[nd] = *(bf16x8*)&sVt[po * 4096 + (nd * 16 + lm) * 64 +
                                        ((c0 ^ (jb << 2)) << 3)];
#pragma unroll
            for (int sub = 0; sub < 4; ++sub)
#pragma unroll
                for (int nd = 0; nd < 4; ++nd)
                    acc[sub][nd] = mfma16(av[nd], pf[sub][jb], acc[sub][nd]);
        }

        // deposit prefetched tile into the OTHER buffer; single barrier publishes it
        int qo = po ^ 1;
        *(bf16x8*)&sK[qo * 4096 + tid * 16] = krA;
        *(bf16x8*)&sK[qo * 4096 + tid * 16 + 8] = krB;
        *(bf16x8*)&sVt[qo * 4096 + tid * 16] = vrA;
        *(bf16x8*)&sVt[qo * 4096 + tid * 16 + 8] = vrB;
        __syncthreads();
        po = qo;
    }

    // l reduction across quads (each quad holds a disjoint key subset)
#pragma unroll
    for (int sub = 0; sub < 4; ++sub) {
        lacc[sub] += __shfl_xor(lacc[sub], 16);
        lacc[sub] += __shfl_xor(lacc[sub], 32);
    }

    if (nsplit == 1) {
#pragma unroll
        for (int sub = 0; sub < 4; ++sub) {
            float inv = 1.f / lacc[sub];
            int row = qrow0 + sub * 16 + lm;
#pragma unroll
            for (int nd = 0; nd < 4; ++nd) {
                bf16x4 o;
#pragma unroll
                for (int r = 0; r < 4; ++r) o[r] = (bf16_t)(acc[sub][nd][r] * inv);
                *(bf16x4*)&O[(size_t)row * 64 + nd * 16 + q * 4] = o;
            }
        }
    } else {
#pragma unroll
        for (int sub = 0; sub < 4; ++sub) {
            int row = qrow0 + sub * 16 + lm;
            size_t base = ((size_t)sp * 16384 + row) * 64;
#pragma unroll
            for (int nd = 0; nd < 4; ++nd) {
                float4 v = {acc[sub][nd][0], acc[sub][nd][1],
                            acc[sub][nd][2], acc[sub][nd][3]};
                *(float4*)&accP[base + nd * 16 + q * 4] = v;
            }
            if (lane < 16) lP[sp * 16384 + row] = lacc[sub];
        }
    }
}

// ---------------- merge key-split partials (plain sums) ----------------
__global__ __launch_bounds__(256) void merge_attn(const float* __restrict__ accP,
                                                  const float* __restrict__ lP,
                                                  bf16_t* __restrict__ O, int nsplit) {
    int idx = blockIdx.x * 256 + threadIdx.x;
    int row = idx >> 4, dh4 = (idx & 15) * 4;
    float4 num = {0.f, 0.f, 0.f, 0.f};
    float den = 0.f;
    for (int s = 0; s < nsplit; ++s) {
        float4 a = *(const float4*)&accP[((size_t)s * 16384 + row) * 64 + dh4];
        num.x += a.x; num.y += a.y; num.z += a.z; num.w += a.w;
        den += lP[s * 16384 + row];
    }
    float inv = 1.f / den;
    bf16x4 o;
    o[0] = (bf16_t)(num.x * inv); o[1] = (bf16_t)(num.y * inv);
    o[2] = (bf16_t)(num.z * inv); o[3] = (bf16_t)(num.w * inv);
    *(bf16x4*)&O[(size_t)row * 64 + dh4] = o;
}

// ---------------- launch ----------------
extern "C" void kernel_launch(void* const* d_in, const int* in_sizes, int n_in,
                              void* d_out, int out_size, void* d_ws, size_t ws_size,
                              hipStream_t stream) {
    const float* x    = (const float*)d_in[0];  // 2048 x 1024
    const float* Wq   = (const float*)d_in[1];  // 1024 x 512
    const float* Wkv  = (const float*)d_in[2];  // 1024 x 1024
    const float* Wout = (const float*)d_in[3];  // 512 x 1024
    const float* bout = (const float*)d_in[4];  // 1024

    char* ws = (char*)d_ws;
    bf16_t* QK    = (bf16_t*)ws;
    bf16_t* Vt    = (bf16_t*)(ws + 4194304);
    bf16_t* Ob    = (bf16_t*)(ws + 6291456);
    bf16_t* xb    = (bf16_t*)(ws + 8388608);
    bf16_t* WtQKV = (bf16_t*)(ws + 12582912);
    bf16_t* WtOut = (bf16_t*)(ws + 15728640);
    float*  accP  = (float*)(ws + 16777216);

    int nsplit = (ws_size >= (size_t)16777216 + 8 * 4259840) ? 8
               : (ws_size >= (size_t)16777216 + 4 * 4259840) ? 4
               : (ws_size >= (size_t)16777216 + 2 * 4259840) ? 2 : 1;
    float* lP = (float*)(ws + 16777216 + (size_t)nsplit * 4194304);

    prep_all<<<3072, 256, 0, stream>>>(x, xb, Wq, Wkv, Wout, WtQKV, WtOut);

    // [QK | Vt] = xb @ WtQKV^T; Q cols scaled by DH^-0.5*log2(e); V cols transposed
    gemm_bt<0, 2><<<dim3(32, 24), 256, 0, stream>>>(
        xb, WtQKV, nullptr, QK, Vt, 1024, 1024, 1024, 1024, 1024,
        0.18033688011112042f, 512);

    flash_attn<<<dim3(64, nsplit), 256, 0, stream>>>(QK, Vt, Ob, accP, lP,
                                                     16384 / nsplit, nsplit);
    if (nsplit > 1)
        merge_attn<<<1024, 256, 0, stream>>>(accP, lP, Ob, nsplit);

    // out = Ob @ WtOut^T + bout (fp32 out)
    gemm_bt<1, 2><<<dim3(32, 16), 256, 0, stream>>>(
        Ob, WtOut, bout, d_out, nullptr, 1 << 30, 512, 512, 512, 1024,
        1.0f, 0);
}